// Round 9
// baseline (961.736 us; speedup 1.0000x reference)
//
#include <hip/hip_runtime.h>
#include <stdint.h>

// BioGNN: out = exp(log_nu)*dx - exp(log_decay)*x + exp(log_growth)
// dx = has_any ? (has_act ? num : 1) / (1 + num + inh_sum) : 0
//
// Round-6 evidence: agent-scope atomicAdd is executed PAST the per-XCD L2
// (WRITE_SIZE == 31 B/edge == one fabric transaction per atomic; 20 G/s cap).
// This round: per-XCD partial accumulators + sc0=sc1=0 global_atomic_add_f32
// (executes in the LOCAL XCD L2; correct because each partial buffer is only
// ever touched by one XCD, and dispatch-boundary L2 writeback makes it
// visible to the finalize kernel).

__device__ __forceinline__ void atomic_add_f32_l2(float* p, float v) {
    // no sc0 (no return), no sc1 -> RMW executes in the local XCD's L2.
    asm volatile("global_atomic_add_f32 %0, %1, off" :: "v"(p), "v"(v) : "memory");
}

__device__ __forceinline__ int xcc_id() {
    // hwreg(HW_REG_XCC_ID=20, offset=0, width=4) -> imm = 20 | (3<<11) = 6164
    return (int)__builtin_amdgcn_s_getreg(6164) & 7;
}

// ---------- per-XCD path ----------
__global__ __launch_bounds__(256) void edge_kernel_xcd(
    const int* __restrict__ src, const int* __restrict__ dst,
    const float* __restrict__ k, const float* __restrict__ hill,
    const float* __restrict__ x,
    float* __restrict__ sumBase, int stride,
    int nEdges)
{
    float* sum = sumBase + (size_t)xcc_id() * (size_t)stride;
    int tid = blockIdx.x * blockDim.x + threadIdx.x;
    int e = tid * 4;
    if (e + 3 < nEdges) {
        int4   s4 = *reinterpret_cast<const int4*>(src + e);
        int4   d4 = *reinterpret_cast<const int4*>(dst + e);
        float4 k4 = *reinterpret_cast<const float4*>(k + e);
        float4 h4 = *reinterpret_cast<const float4*>(hill + e);

        float x0 = x[s4.x], x1 = x[s4.y], x2 = x[s4.z], x3 = x[s4.w];

        float c0 = k4.x * ((h4.x == 2.0f) ? x0 * x0 : __powf(x0, h4.x));
        float c1 = k4.y * ((h4.y == 2.0f) ? x1 * x1 : __powf(x1, h4.y));
        float c2 = k4.z * ((h4.z == 2.0f) ? x2 * x2 : __powf(x2, h4.z));
        float c3 = k4.w * ((h4.w == 2.0f) ? x3 * x3 : __powf(x3, h4.w));

        atomic_add_f32_l2(&sum[d4.x], c0);
        atomic_add_f32_l2(&sum[d4.y], c1);
        atomic_add_f32_l2(&sum[d4.z], c2);
        atomic_add_f32_l2(&sum[d4.w], c3);
    } else {
        for (int i = e; i < nEdges; ++i) {
            int s = src[i], d = dst[i];
            float kv = k[i], hv = hill[i];
            float xv = x[s];
            float c = kv * ((hv == 2.0f) ? xv * xv : __powf(xv, hv));
            atomic_add_f32_l2(&sum[d], c);
        }
    }
}

__global__ __launch_bounds__(256) void finalize_kernel_xcd(
    const float* __restrict__ x,
    const float* __restrict__ np, const float* __restrict__ ip, int stride,
    const float* __restrict__ log_decay, const float* __restrict__ log_growth,
    const float* __restrict__ log_nu,
    float* __restrict__ out, int n)
{
    int tid = blockIdx.x * blockDim.x + threadIdx.x;
    int b = tid * 4;
    if (b + 3 < n) {
        float4 nm = make_float4(0.f, 0.f, 0.f, 0.f);
        float4 ih = make_float4(0.f, 0.f, 0.f, 0.f);
#pragma unroll
        for (int q = 0; q < 8; ++q) {
            float4 t = *reinterpret_cast<const float4*>(np + (size_t)q * stride + b);
            nm.x += t.x; nm.y += t.y; nm.z += t.z; nm.w += t.w;
            float4 u = *reinterpret_cast<const float4*>(ip + (size_t)q * stride + b);
            ih.x += u.x; ih.y += u.y; ih.z += u.z; ih.w += u.w;
        }
        float4 xv = *reinterpret_cast<const float4*>(x + b);
        float4 ld = *reinterpret_cast<const float4*>(log_decay + b);
        float4 lg = *reinterpret_cast<const float4*>(log_growth + b);
        float4 lv = *reinterpret_cast<const float4*>(log_nu + b);

        float4 o;
        {
            bool ha = nm.x > 0.0f, hany = (nm.x + ih.x) > 0.0f;
            float numr = ha ? nm.x : 1.0f;
            float dx = hany ? numr / (1.0f + nm.x + ih.x) : 0.0f;
            o.x = __expf(lv.x) * dx - __expf(ld.x) * xv.x + __expf(lg.x);
        }
        {
            bool ha = nm.y > 0.0f, hany = (nm.y + ih.y) > 0.0f;
            float numr = ha ? nm.y : 1.0f;
            float dx = hany ? numr / (1.0f + nm.y + ih.y) : 0.0f;
            o.y = __expf(lv.y) * dx - __expf(ld.y) * xv.y + __expf(lg.y);
        }
        {
            bool ha = nm.z > 0.0f, hany = (nm.z + ih.z) > 0.0f;
            float numr = ha ? nm.z : 1.0f;
            float dx = hany ? numr / (1.0f + nm.z + ih.z) : 0.0f;
            o.z = __expf(lv.z) * dx - __expf(ld.z) * xv.z + __expf(lg.z);
        }
        {
            bool ha = nm.w > 0.0f, hany = (nm.w + ih.w) > 0.0f;
            float numr = ha ? nm.w : 1.0f;
            float dx = hany ? numr / (1.0f + nm.w + ih.w) : 0.0f;
            o.w = __expf(lv.w) * dx - __expf(ld.w) * xv.w + __expf(lg.w);
        }
        *reinterpret_cast<float4*>(out + b) = o;
    } else {
        for (int i = b; i < n; ++i) {
            float nmv = 0.f, ihv = 0.f;
            for (int q = 0; q < 8; ++q) {
                nmv += np[(size_t)q * stride + i];
                ihv += ip[(size_t)q * stride + i];
            }
            bool ha = nmv > 0.0f, hany = (nmv + ihv) > 0.0f;
            float numr = ha ? nmv : 1.0f;
            float dx = hany ? numr / (1.0f + nmv + ihv) : 0.0f;
            out[i] = __expf(log_nu[i]) * dx - __expf(log_decay[i]) * x[i] + __expf(log_growth[i]);
        }
    }
}

// ---------- fallback path (round-4 verified: agent atomics, single buffer) ----------
__global__ __launch_bounds__(256) void edge_kernel(
    const int* __restrict__ src, const int* __restrict__ dst,
    const float* __restrict__ k, const float* __restrict__ hill,
    const float* __restrict__ x,
    float* __restrict__ sum,
    int nEdges)
{
    int tid = blockIdx.x * blockDim.x + threadIdx.x;
    int e = tid * 4;
    if (e + 3 < nEdges) {
        int4   s4 = *reinterpret_cast<const int4*>(src + e);
        int4   d4 = *reinterpret_cast<const int4*>(dst + e);
        float4 k4 = *reinterpret_cast<const float4*>(k + e);
        float4 h4 = *reinterpret_cast<const float4*>(hill + e);
        float x0 = x[s4.x], x1 = x[s4.y], x2 = x[s4.z], x3 = x[s4.w];
        float c0 = k4.x * ((h4.x == 2.0f) ? x0 * x0 : __powf(x0, h4.x));
        float c1 = k4.y * ((h4.y == 2.0f) ? x1 * x1 : __powf(x1, h4.y));
        float c2 = k4.z * ((h4.z == 2.0f) ? x2 * x2 : __powf(x2, h4.z));
        float c3 = k4.w * ((h4.w == 2.0f) ? x3 * x3 : __powf(x3, h4.w));
        atomicAdd(&sum[d4.x], c0);
        atomicAdd(&sum[d4.y], c1);
        atomicAdd(&sum[d4.z], c2);
        atomicAdd(&sum[d4.w], c3);
    } else {
        for (int i = e; i < nEdges; ++i) {
            int s = src[i], d = dst[i];
            float xv = x[s];
            float c = k[i] * ((hill[i] == 2.0f) ? xv * xv : __powf(xv, hill[i]));
            atomicAdd(&sum[d], c);
        }
    }
}

__global__ __launch_bounds__(256) void finalize_kernel(
    const float* __restrict__ x,
    const float* __restrict__ num, const float* __restrict__ inh,
    const float* __restrict__ log_decay, const float* __restrict__ log_growth,
    const float* __restrict__ log_nu,
    float* __restrict__ out, int n)
{
    int tid = blockIdx.x * blockDim.x + threadIdx.x;
    int i = tid;
    if (i < n) {
        float nmv = num[i], ihv = inh[i];
        bool ha = nmv > 0.0f, hany = (nmv + ihv) > 0.0f;
        float numr = ha ? nmv : 1.0f;
        float dx = hany ? numr / (1.0f + nmv + ihv) : 0.0f;
        out[i] = __expf(log_nu[i]) * dx - __expf(log_decay[i]) * x[i] + __expf(log_growth[i]);
    }
}

extern "C" void kernel_launch(void* const* d_in, const int* in_sizes, int n_in,
                              void* d_out, int out_size, void* d_ws, size_t ws_size,
                              hipStream_t stream)
{
    const float* x          = (const float*)d_in[0];
    const int*   act_src    = (const int*)d_in[1];
    const int*   act_dst    = (const int*)d_in[2];
    const float* act_k      = (const float*)d_in[3];
    const float* act_hill   = (const float*)d_in[4];
    const int*   inh_src    = (const int*)d_in[5];
    const int*   inh_dst    = (const int*)d_in[6];
    const float* inh_k      = (const float*)d_in[7];
    const float* inh_hill   = (const float*)d_in[8];
    const float* log_decay  = (const float*)d_in[9];
    const float* log_growth = (const float*)d_in[10];
    const float* log_nu     = (const float*)d_in[11];
    float* out = (float*)d_out;

    const int n    = in_sizes[0];   // 500,000
    const int nAct = in_sizes[1];   // 8,000,000
    const int nInh = in_sizes[5];   // 8,000,000

    const int BLK = 256;
    int actBlocks = ((nAct + 3) / 4 + BLK - 1) / BLK;
    int inhBlocks = ((nInh + 3) / 4 + BLK - 1) / BLK;

    // per-XCD layout: 8 partial buffers per sum, stride padded to 512B
    int stride = (n + 127) & ~127;
    size_t need = (size_t)stride * 4 * 16;   // 8 act + 8 inh partials

    if (ws_size >= need) {
        float* np = (float*)d_ws;
        float* ip = np + (size_t)stride * 8;
        hipMemsetAsync(d_ws, 0, need, stream);

        edge_kernel_xcd<<<actBlocks, BLK, 0, stream>>>(act_src, act_dst, act_k, act_hill,
                                                       x, np, stride, nAct);
        edge_kernel_xcd<<<inhBlocks, BLK, 0, stream>>>(inh_src, inh_dst, inh_k, inh_hill,
                                                       x, ip, stride, nInh);

        int finBlocks = ((n + 3) / 4 + BLK - 1) / BLK;
        finalize_kernel_xcd<<<finBlocks, BLK, 0, stream>>>(x, np, ip, stride,
                                                           log_decay, log_growth, log_nu,
                                                           out, n);
    } else {
        // fallback: round-4 verified path
        char* ws = (char*)d_ws;
        float* num = (float*)ws;
        float* inh = (float*)(ws + (size_t)n * 4);
        hipMemsetAsync(d_ws, 0, (size_t)n * 8, stream);

        edge_kernel<<<actBlocks, BLK, 0, stream>>>(act_src, act_dst, act_k, act_hill,
                                                   x, num, nAct);
        edge_kernel<<<inhBlocks, BLK, 0, stream>>>(inh_src, inh_dst, inh_k, inh_hill,
                                                   x, inh, nInh);

        int finBlocks = (n + BLK - 1) / BLK;
        finalize_kernel<<<finBlocks, BLK, 0, stream>>>(x, num, inh,
                                                       log_decay, log_growth, log_nu,
                                                       out, n);
    }
}

// Round 10
// 628.933 us; speedup vs baseline: 1.5292x; 1.5292x over previous
//
#include <hip/hip_runtime.h>
#include <stdint.h>

// BioGNN: out = exp(log_nu)*dx - exp(log_decay)*x + exp(log_growth)
// dx = has_any ? (has_act ? num : 1) / (1 + num + inh_sum) : 0
//
// Round-9 evidence: fp32 global atomics execute past L2 (write-through,
// 31 B/edge to HBM) regardless of scope/cache bits; ~20 G/s cap; CU-side idle.
// This round: eliminate global fp atomics via dst-binning:
//   scatter: bin edges into 123 buckets (4096 nodes) with LDS counts +
//            one cursor atomic per (block,bucket); plain cached stores.
//   accum:   per-bucket LDS atomicAdd, then exclusive plain += into sums.
// Overflow edges (never, for uniform dst) use direct atomic -> always correct.

#define BSHIFT 12
#define BSIZE  (1 << BSHIFT)          // 4096 nodes / bucket
#define CHUNK  (4 * 1024 * 1024)      // edges per chunk-pass
#define THR    1024
#define EPB    (THR * 16)             // 16384 edges per scatter block
#define INVALID_LB 0xFFFFFFFFu

__device__ __forceinline__ float hill_term(float kv, float hv, float xv) {
    return kv * ((hv == 2.0f) ? xv * xv : __powf(xv, hv));
}

// ---------------- scatter: edges -> bucketed (c, loc) ----------------
__global__ __launch_bounds__(THR) void scatter_kernel(
    const int* __restrict__ src, const int* __restrict__ dst,
    const float* __restrict__ k, const float* __restrict__ hill,
    const float* __restrict__ x,
    float* __restrict__ cbuf, unsigned short* __restrict__ dloc,
    int* __restrict__ cur,           // [nb] cursors for this chunk-pass
    float* __restrict__ sums,        // overflow fallback target
    int chunkStart, int chunkEnd, int nb, int cap)
{
    __shared__ int cntA[256];
    __shared__ int baseB[256];
    __shared__ int cur2[256];
    const int tid = threadIdx.x;
    for (int i = tid; i < nb; i += THR) { cntA[i] = 0; cur2[i] = 0; }
    __syncthreads();

    float cv[16];
    unsigned int lb[16];

    const int eb = chunkStart + blockIdx.x * EPB;

#define PROC(M, S, D, K, H)                                           \
    {                                                                  \
        int   _d = (D);                                                \
        float _x = x[(S)];                                             \
        cv[M] = hill_term((K), (H), _x);                               \
        int _b = _d >> BSHIFT;                                         \
        lb[M] = ((unsigned)_b << 16) | (unsigned)(_d & (BSIZE - 1));   \
        atomicAdd(&cntA[_b], 1);                                       \
    }

#pragma unroll
    for (int r = 0; r < 4; ++r) {
        const int m0 = r * 4;
        const int e = eb + r * (THR * 4) + tid * 4;
        if (e + 3 < chunkEnd) {
            int4   s4 = *reinterpret_cast<const int4*>(src + e);
            int4   d4 = *reinterpret_cast<const int4*>(dst + e);
            float4 k4 = *reinterpret_cast<const float4*>(k + e);
            float4 h4 = *reinterpret_cast<const float4*>(hill + e);
            PROC(m0 + 0, s4.x, d4.x, k4.x, h4.x);
            PROC(m0 + 1, s4.y, d4.y, k4.y, h4.y);
            PROC(m0 + 2, s4.z, d4.z, k4.z, h4.z);
            PROC(m0 + 3, s4.w, d4.w, k4.w, h4.w);
        } else {
#pragma unroll
            for (int j = 0; j < 4; ++j) {
                const int e2 = e + j;
                if (e2 < chunkEnd) {
                    PROC(m0 + j, src[e2], dst[e2], k[e2], hill[e2]);
                } else {
                    lb[m0 + j] = INVALID_LB;
                }
            }
        }
    }
#undef PROC

    __syncthreads();
    if (tid < nb) {
        int c = cntA[tid];
        baseB[tid] = (c > 0) ? atomicAdd(&cur[tid], c) : 0;
    }
    __syncthreads();

#pragma unroll
    for (int m = 0; m < 16; ++m) {
        unsigned int v = lb[m];
        if (v != INVALID_LB) {
            int b   = (int)(v >> 16);
            int loc = (int)(v & 0xFFFFu);
            int rank = atomicAdd(&cur2[b], 1);
            int pos  = baseB[b] + rank;
            if (pos < cap) {
                size_t s = (size_t)b * (size_t)cap + (size_t)pos;
                cbuf[s] = cv[m];
                dloc[s] = (unsigned short)loc;
            } else {
                // overflow (never for uniform dst): always-correct fallback
                atomicAdd(&sums[(b << BSHIFT) + loc], cv[m]);
            }
        }
    }
}

// ---------------- accum: bucket segment -> LDS -> sums ----------------
__global__ __launch_bounds__(THR) void accum_kernel(
    const float* __restrict__ cbuf, const unsigned short* __restrict__ dloc,
    const int* __restrict__ cur, int cap,
    float* __restrict__ sums, int n)
{
    __shared__ float acc[BSIZE];
    const int b   = blockIdx.x;
    const int tid = threadIdx.x;
    for (int i = tid; i < BSIZE; i += THR) acc[i] = 0.0f;
    __syncthreads();

    int cnt = cur[b];
    if (cnt > cap) cnt = cap;
    const size_t base = (size_t)b * (size_t)cap;
    for (int i = tid; i < cnt; i += THR) {
        float c  = cbuf[base + i];
        int  loc = dloc[base + i];
        atomicAdd(&acc[loc], c);   // LDS atomic
    }
    __syncthreads();

    const int nodeBase = b << BSHIFT;
    const int lim = min(BSIZE, n - nodeBase);
    for (int i = tid; i < lim; i += THR) {
        float v = acc[i];
        if (v != 0.0f) sums[nodeBase + i] += v;   // exclusive owner: plain RMW
    }
}

// ---------------- finalize (float4, single buffers) ----------------
__global__ __launch_bounds__(256) void finalize_kernel(
    const float* __restrict__ x,
    const float* __restrict__ num, const float* __restrict__ inh,
    const float* __restrict__ log_decay, const float* __restrict__ log_growth,
    const float* __restrict__ log_nu,
    float* __restrict__ out, int n)
{
    int tid = blockIdx.x * blockDim.x + threadIdx.x;
    int b = tid * 4;
    if (b + 3 < n) {
        float4 xv = *reinterpret_cast<const float4*>(x + b);
        float4 nm = *reinterpret_cast<const float4*>(num + b);
        float4 ih = *reinterpret_cast<const float4*>(inh + b);
        float4 ld = *reinterpret_cast<const float4*>(log_decay + b);
        float4 lg = *reinterpret_cast<const float4*>(log_growth + b);
        float4 lv = *reinterpret_cast<const float4*>(log_nu + b);
        float4 o;
        {
            bool ha = nm.x > 0.0f, hany = (nm.x + ih.x) > 0.0f;
            float dx = hany ? (ha ? nm.x : 1.0f) / (1.0f + nm.x + ih.x) : 0.0f;
            o.x = __expf(lv.x) * dx - __expf(ld.x) * xv.x + __expf(lg.x);
        }
        {
            bool ha = nm.y > 0.0f, hany = (nm.y + ih.y) > 0.0f;
            float dx = hany ? (ha ? nm.y : 1.0f) / (1.0f + nm.y + ih.y) : 0.0f;
            o.y = __expf(lv.y) * dx - __expf(ld.y) * xv.y + __expf(lg.y);
        }
        {
            bool ha = nm.z > 0.0f, hany = (nm.z + ih.z) > 0.0f;
            float dx = hany ? (ha ? nm.z : 1.0f) / (1.0f + nm.z + ih.z) : 0.0f;
            o.z = __expf(lv.z) * dx - __expf(ld.z) * xv.z + __expf(lg.z);
        }
        {
            bool ha = nm.w > 0.0f, hany = (nm.w + ih.w) > 0.0f;
            float dx = hany ? (ha ? nm.w : 1.0f) / (1.0f + nm.w + ih.w) : 0.0f;
            o.w = __expf(lv.w) * dx - __expf(ld.w) * xv.w + __expf(lg.w);
        }
        *reinterpret_cast<float4*>(out + b) = o;
    } else {
        for (int i = b; i < n; ++i) {
            float nmv = num[i], ihv = inh[i];
            bool ha = nmv > 0.0f, hany = (nmv + ihv) > 0.0f;
            float dx = hany ? (ha ? nmv : 1.0f) / (1.0f + nmv + ihv) : 0.0f;
            out[i] = __expf(log_nu[i]) * dx - __expf(log_decay[i]) * x[i] + __expf(log_growth[i]);
        }
    }
}

// ---------------- fallback (round-6 verified: agent atomics) ----------------
__global__ __launch_bounds__(256) void edge_kernel_fb(
    const int* __restrict__ src, const int* __restrict__ dst,
    const float* __restrict__ k, const float* __restrict__ hill,
    const float* __restrict__ x, float* __restrict__ sum, int nEdges)
{
    int tid = blockIdx.x * blockDim.x + threadIdx.x;
    int e = tid * 4;
    if (e + 3 < nEdges) {
        int4   s4 = *reinterpret_cast<const int4*>(src + e);
        int4   d4 = *reinterpret_cast<const int4*>(dst + e);
        float4 k4 = *reinterpret_cast<const float4*>(k + e);
        float4 h4 = *reinterpret_cast<const float4*>(hill + e);
        atomicAdd(&sum[d4.x], hill_term(k4.x, h4.x, x[s4.x]));
        atomicAdd(&sum[d4.y], hill_term(k4.y, h4.y, x[s4.y]));
        atomicAdd(&sum[d4.z], hill_term(k4.z, h4.z, x[s4.z]));
        atomicAdd(&sum[d4.w], hill_term(k4.w, h4.w, x[s4.w]));
    } else {
        for (int i = e; i < nEdges; ++i)
            atomicAdd(&sum[dst[i]], hill_term(k[i], hill[i], x[src[i]]));
    }
}

static inline size_t align16(size_t v) { return (v + 15) & ~(size_t)15; }

extern "C" void kernel_launch(void* const* d_in, const int* in_sizes, int n_in,
                              void* d_out, int out_size, void* d_ws, size_t ws_size,
                              hipStream_t stream)
{
    const float* x          = (const float*)d_in[0];
    const int*   act_src    = (const int*)d_in[1];
    const int*   act_dst    = (const int*)d_in[2];
    const float* act_k      = (const float*)d_in[3];
    const float* act_hill   = (const float*)d_in[4];
    const int*   inh_src    = (const int*)d_in[5];
    const int*   inh_dst    = (const int*)d_in[6];
    const float* inh_k      = (const float*)d_in[7];
    const float* inh_hill   = (const float*)d_in[8];
    const float* log_decay  = (const float*)d_in[9];
    const float* log_growth = (const float*)d_in[10];
    const float* log_nu     = (const float*)d_in[11];
    float* out = (float*)d_out;

    const int n    = in_sizes[0];   // 500,000
    const int nAct = in_sizes[1];   // 8,000,000
    const int nInh = in_sizes[5];   // 8,000,000

    const int nb  = (n + BSIZE - 1) >> BSHIFT;     // 123 buckets
    const int cap = 36000;                          // ~mean+10 sigma per chunk
    const int npassAct = (nAct + CHUNK - 1) / CHUNK;
    const int npassInh = (nInh + CHUNK - 1) / CHUNK;
    const int npass = npassAct + npassInh;

    char* ws = (char*)d_ws;
    size_t off = 0;
    float* num  = (float*)(ws + off); off += align16((size_t)n * 4);
    float* inh  = (float*)(ws + off); off += align16((size_t)n * 4);
    int*   cur  = (int*)(ws + off);   off += align16((size_t)npass * nb * 4);
    size_t memsetBytes = off;
    float* cbuf = (float*)(ws + off); off += align16((size_t)nb * cap * 4);
    unsigned short* dloc = (unsigned short*)(ws + off); off += (size_t)nb * cap * 2;
    size_t need = off;

    if (ws_size >= need && nb <= 256) {
        // zero sums + all cursors in one memset (cbuf/dloc fully overwritten before read)
        hipMemsetAsync(d_ws, 0, memsetBytes, stream);

        int pass = 0;
        // activation chunks
        for (int s = 0; s < nAct; s += CHUNK, ++pass) {
            int cend = s + CHUNK < nAct ? s + CHUNK : nAct;
            int blocks = (cend - s + EPB - 1) / EPB;
            scatter_kernel<<<blocks, THR, 0, stream>>>(
                act_src, act_dst, act_k, act_hill, x,
                cbuf, dloc, cur + (size_t)pass * nb, num, s, cend, nb, cap);
            accum_kernel<<<nb, THR, 0, stream>>>(
                cbuf, dloc, cur + (size_t)pass * nb, cap, num, n);
        }
        // inhibition chunks
        for (int s = 0; s < nInh; s += CHUNK, ++pass) {
            int cend = s + CHUNK < nInh ? s + CHUNK : nInh;
            int blocks = (cend - s + EPB - 1) / EPB;
            scatter_kernel<<<blocks, THR, 0, stream>>>(
                inh_src, inh_dst, inh_k, inh_hill, x,
                cbuf, dloc, cur + (size_t)pass * nb, inh, s, cend, nb, cap);
            accum_kernel<<<nb, THR, 0, stream>>>(
                cbuf, dloc, cur + (size_t)pass * nb, cap, inh, n);
        }

        int finBlocks = ((n + 3) / 4 + 255) / 256;
        finalize_kernel<<<finBlocks, 256, 0, stream>>>(
            x, num, inh, log_decay, log_growth, log_nu, out, n);
    } else {
        // round-6 verified fallback: agent atomics
        float* fnum = (float*)ws;
        float* finh = (float*)(ws + (size_t)n * 4);
        hipMemsetAsync(d_ws, 0, (size_t)n * 8, stream);
        const int BLK = 256;
        int actBlocks = ((nAct + 3) / 4 + BLK - 1) / BLK;
        int inhBlocks = ((nInh + 3) / 4 + BLK - 1) / BLK;
        edge_kernel_fb<<<actBlocks, BLK, 0, stream>>>(act_src, act_dst, act_k, act_hill, x, fnum, nAct);
        edge_kernel_fb<<<inhBlocks, BLK, 0, stream>>>(inh_src, inh_dst, inh_k, inh_hill, x, finh, nInh);
        int finBlocks = ((n + 3) / 4 + BLK - 1) / BLK;
        finalize_kernel<<<finBlocks, BLK, 0, stream>>>(x, fnum, finh, log_decay, log_growth, log_nu, out, n);
    }
}

// Round 14
// 573.269 us; speedup vs baseline: 1.6776x; 1.0971x over previous
//
#include <hip/hip_runtime.h>
#include <stdint.h>

// BioGNN: out = exp(log_nu)*dx - exp(log_decay)*x + exp(log_growth)
// dx = has_any ? (has_act ? num : 1) / (1 + num + inh_sum) : 0
//
// Round-10 evidence: binning works (954->629us) but scatter spilled
// (VGPR_Count=32 with 32+ live values -> scratch traffic) and accum had only
// 123 blocks + scalar dependent loads. This round: 8 edges/thread +
// launch_bounds(1024,4) (128 VGPR budget, no spill); BSIZE 2048 (245 accum
// blocks) + float4/ushort4 vectorized record loads in accum.

#define BSHIFT 11
#define BSIZE  (1 << BSHIFT)          // 2048 nodes / bucket
#define CHUNK  (4 * 1024 * 1024)      // edges per chunk-pass
#define THR    1024
#define EPT    8                      // edges per thread (live regs: 2*EPT)
#define EPB    (THR * EPT)            // 8192 edges per scatter block
#define INVALID_LB 0xFFFFFFFFu

__device__ __forceinline__ float hill_term(float kv, float hv, float xv) {
    return kv * ((hv == 2.0f) ? xv * xv : __powf(xv, hv));
}

// ---------------- scatter: edges -> bucketed (c, loc) ----------------
__global__ __launch_bounds__(THR, 4) void scatter_kernel(
    const int* __restrict__ src, const int* __restrict__ dst,
    const float* __restrict__ k, const float* __restrict__ hill,
    const float* __restrict__ x,
    float* __restrict__ cbuf, unsigned short* __restrict__ dloc,
    int* __restrict__ cur,           // [nb] cursors for this chunk-pass
    float* __restrict__ sums,        // overflow fallback target
    int chunkStart, int chunkEnd, int nb, int cap)
{
    __shared__ int cntA[256];
    __shared__ int baseB[256];
    __shared__ int cur2[256];
    const int tid = threadIdx.x;
    for (int i = tid; i < nb; i += THR) { cntA[i] = 0; cur2[i] = 0; }
    __syncthreads();

    float cv[EPT];
    unsigned int lb[EPT];

    const int eb = chunkStart + blockIdx.x * EPB;

#define PROC(M, S, D, K, H)                                           \
    {                                                                  \
        int   _d = (D);                                                \
        float _x = x[(S)];                                             \
        cv[M] = hill_term((K), (H), _x);                               \
        int _b = _d >> BSHIFT;                                         \
        lb[M] = ((unsigned)_b << 16) | (unsigned)(_d & (BSIZE - 1));   \
        atomicAdd(&cntA[_b], 1);                                       \
    }

#pragma unroll
    for (int r = 0; r < EPT / 4; ++r) {
        const int m0 = r * 4;
        const int e = eb + r * (THR * 4) + tid * 4;
        if (e + 3 < chunkEnd) {
            int4   s4 = *reinterpret_cast<const int4*>(src + e);
            int4   d4 = *reinterpret_cast<const int4*>(dst + e);
            float4 k4 = *reinterpret_cast<const float4*>(k + e);
            float4 h4 = *reinterpret_cast<const float4*>(hill + e);
            PROC(m0 + 0, s4.x, d4.x, k4.x, h4.x);
            PROC(m0 + 1, s4.y, d4.y, k4.y, h4.y);
            PROC(m0 + 2, s4.z, d4.z, k4.z, h4.z);
            PROC(m0 + 3, s4.w, d4.w, k4.w, h4.w);
        } else {
#pragma unroll
            for (int j = 0; j < 4; ++j) {
                const int e2 = e + j;
                if (e2 < chunkEnd) {
                    PROC(m0 + j, src[e2], dst[e2], k[e2], hill[e2]);
                } else {
                    lb[m0 + j] = INVALID_LB;
                }
            }
        }
    }
#undef PROC

    __syncthreads();
    if (tid < nb) {
        int c = cntA[tid];
        baseB[tid] = (c > 0) ? atomicAdd(&cur[tid], c) : 0;
    }
    __syncthreads();

#pragma unroll
    for (int m = 0; m < EPT; ++m) {
        unsigned int v = lb[m];
        if (v != INVALID_LB) {
            int b   = (int)(v >> 16);
            int loc = (int)(v & 0xFFFFu);
            int rank = atomicAdd(&cur2[b], 1);
            int pos  = baseB[b] + rank;
            if (pos < cap) {
                size_t s = (size_t)b * (size_t)cap + (size_t)pos;
                cbuf[s] = cv[m];
                dloc[s] = (unsigned short)loc;
            } else {
                // overflow (never for uniform dst): always-correct fallback
                atomicAdd(&sums[(b << BSHIFT) + loc], cv[m]);
            }
        }
    }
}

// ---------------- accum: bucket segment -> LDS -> sums ----------------
__global__ __launch_bounds__(THR, 4) void accum_kernel(
    const float* __restrict__ cbuf, const unsigned short* __restrict__ dloc,
    const int* __restrict__ cur, int cap,
    float* __restrict__ sums, int n)
{
    __shared__ float acc[BSIZE];
    const int b   = blockIdx.x;
    const int tid = threadIdx.x;
#pragma unroll
    for (int i = tid; i < BSIZE; i += THR) acc[i] = 0.0f;
    __syncthreads();

    int cnt = cur[b];
    if (cnt > cap) cnt = cap;
    const size_t base = (size_t)b * (size_t)cap;

    // vectorized: each thread takes 4 consecutive records; wave reads 1KB line-dense
    for (int i = tid * 4; i < cnt; i += THR * 4) {
        if (i + 3 < cnt) {
            float4  c4 = *reinterpret_cast<const float4*>(cbuf + base + i);
            ushort4 l4 = *reinterpret_cast<const ushort4*>(dloc + base + i);
            atomicAdd(&acc[l4.x], c4.x);
            atomicAdd(&acc[l4.y], c4.y);
            atomicAdd(&acc[l4.z], c4.z);
            atomicAdd(&acc[l4.w], c4.w);
        } else {
            for (int j = i; j < cnt; ++j)
                atomicAdd(&acc[dloc[base + j]], cbuf[base + j]);
        }
    }
    __syncthreads();

    const int nodeBase = b << BSHIFT;
    const int lim = min(BSIZE, n - nodeBase);
    for (int i = tid; i < lim; i += THR) {
        float v = acc[i];
        if (v != 0.0f) sums[nodeBase + i] += v;   // exclusive owner: plain RMW
    }
}

// ---------------- finalize (float4, single buffers) ----------------
__global__ __launch_bounds__(256) void finalize_kernel(
    const float* __restrict__ x,
    const float* __restrict__ num, const float* __restrict__ inh,
    const float* __restrict__ log_decay, const float* __restrict__ log_growth,
    const float* __restrict__ log_nu,
    float* __restrict__ out, int n)
{
    int tid = blockIdx.x * blockDim.x + threadIdx.x;
    int b = tid * 4;
    if (b + 3 < n) {
        float4 xv = *reinterpret_cast<const float4*>(x + b);
        float4 nm = *reinterpret_cast<const float4*>(num + b);
        float4 ih = *reinterpret_cast<const float4*>(inh + b);
        float4 ld = *reinterpret_cast<const float4*>(log_decay + b);
        float4 lg = *reinterpret_cast<const float4*>(log_growth + b);
        float4 lv = *reinterpret_cast<const float4*>(log_nu + b);
        float4 o;
        {
            bool ha = nm.x > 0.0f, hany = (nm.x + ih.x) > 0.0f;
            float dx = hany ? (ha ? nm.x : 1.0f) / (1.0f + nm.x + ih.x) : 0.0f;
            o.x = __expf(lv.x) * dx - __expf(ld.x) * xv.x + __expf(lg.x);
        }
        {
            bool ha = nm.y > 0.0f, hany = (nm.y + ih.y) > 0.0f;
            float dx = hany ? (ha ? nm.y : 1.0f) / (1.0f + nm.y + ih.y) : 0.0f;
            o.y = __expf(lv.y) * dx - __expf(ld.y) * xv.y + __expf(lg.y);
        }
        {
            bool ha = nm.z > 0.0f, hany = (nm.z + ih.z) > 0.0f;
            float dx = hany ? (ha ? nm.z : 1.0f) / (1.0f + nm.z + ih.z) : 0.0f;
            o.z = __expf(lv.z) * dx - __expf(ld.z) * xv.z + __expf(lg.z);
        }
        {
            bool ha = nm.w > 0.0f, hany = (nm.w + ih.w) > 0.0f;
            float dx = hany ? (ha ? nm.w : 1.0f) / (1.0f + nm.w + ih.w) : 0.0f;
            o.w = __expf(lv.w) * dx - __expf(ld.w) * xv.w + __expf(lg.w);
        }
        *reinterpret_cast<float4*>(out + b) = o;
    } else {
        for (int i = b; i < n; ++i) {
            float nmv = num[i], ihv = inh[i];
            bool ha = nmv > 0.0f, hany = (nmv + ihv) > 0.0f;
            float dx = hany ? (ha ? nmv : 1.0f) / (1.0f + nmv + ihv) : 0.0f;
            out[i] = __expf(log_nu[i]) * dx - __expf(log_decay[i]) * x[i] + __expf(log_growth[i]);
        }
    }
}

// ---------------- fallback (round-6 verified: agent atomics) ----------------
__global__ __launch_bounds__(256) void edge_kernel_fb(
    const int* __restrict__ src, const int* __restrict__ dst,
    const float* __restrict__ k, const float* __restrict__ hill,
    const float* __restrict__ x, float* __restrict__ sum, int nEdges)
{
    int tid = blockIdx.x * blockDim.x + threadIdx.x;
    int e = tid * 4;
    if (e + 3 < nEdges) {
        int4   s4 = *reinterpret_cast<const int4*>(src + e);
        int4   d4 = *reinterpret_cast<const int4*>(dst + e);
        float4 k4 = *reinterpret_cast<const float4*>(k + e);
        float4 h4 = *reinterpret_cast<const float4*>(hill + e);
        atomicAdd(&sum[d4.x], hill_term(k4.x, h4.x, x[s4.x]));
        atomicAdd(&sum[d4.y], hill_term(k4.y, h4.y, x[s4.y]));
        atomicAdd(&sum[d4.z], hill_term(k4.z, h4.z, x[s4.z]));
        atomicAdd(&sum[d4.w], hill_term(k4.w, h4.w, x[s4.w]));
    } else {
        for (int i = e; i < nEdges; ++i)
            atomicAdd(&sum[dst[i]], hill_term(k[i], hill[i], x[src[i]]));
    }
}

static inline size_t align16(size_t v) { return (v + 15) & ~(size_t)15; }

extern "C" void kernel_launch(void* const* d_in, const int* in_sizes, int n_in,
                              void* d_out, int out_size, void* d_ws, size_t ws_size,
                              hipStream_t stream)
{
    const float* x          = (const float*)d_in[0];
    const int*   act_src    = (const int*)d_in[1];
    const int*   act_dst    = (const int*)d_in[2];
    const float* act_k      = (const float*)d_in[3];
    const float* act_hill   = (const float*)d_in[4];
    const int*   inh_src    = (const int*)d_in[5];
    const int*   inh_dst    = (const int*)d_in[6];
    const float* inh_k      = (const float*)d_in[7];
    const float* inh_hill   = (const float*)d_in[8];
    const float* log_decay  = (const float*)d_in[9];
    const float* log_growth = (const float*)d_in[10];
    const float* log_nu     = (const float*)d_in[11];
    float* out = (float*)d_out;

    const int n    = in_sizes[0];   // 500,000
    const int nAct = in_sizes[1];   // 8,000,000
    const int nInh = in_sizes[5];   // 8,000,000

    const int nb  = (n + BSIZE - 1) >> BSHIFT;     // 245 buckets
    const int cap = 18000;                          // mean 16.3K + ~13 sigma
    const int npassAct = (nAct + CHUNK - 1) / CHUNK;
    const int npassInh = (nInh + CHUNK - 1) / CHUNK;
    const int npass = npassAct + npassInh;

    char* ws = (char*)d_ws;
    size_t off = 0;
    float* num  = (float*)(ws + off); off += align16((size_t)n * 4);
    float* inh  = (float*)(ws + off); off += align16((size_t)n * 4);
    int*   cur  = (int*)(ws + off);   off += align16((size_t)npass * nb * 4);
    size_t memsetBytes = off;
    float* cbuf = (float*)(ws + off); off += align16((size_t)nb * cap * 4);
    unsigned short* dloc = (unsigned short*)(ws + off); off += (size_t)nb * cap * 2;
    size_t need = off;

    if (ws_size >= need && nb <= 256) {
        // zero sums + all cursors (cbuf/dloc fully overwritten before read)
        hipMemsetAsync(d_ws, 0, memsetBytes, stream);

        int pass = 0;
        for (int s = 0; s < nAct; s += CHUNK, ++pass) {
            int cend = s + CHUNK < nAct ? s + CHUNK : nAct;
            int blocks = (cend - s + EPB - 1) / EPB;
            scatter_kernel<<<blocks, THR, 0, stream>>>(
                act_src, act_dst, act_k, act_hill, x,
                cbuf, dloc, cur + (size_t)pass * nb, num, s, cend, nb, cap);
            accum_kernel<<<nb, THR, 0, stream>>>(
                cbuf, dloc, cur + (size_t)pass * nb, cap, num, n);
        }
        for (int s = 0; s < nInh; s += CHUNK, ++pass) {
            int cend = s + CHUNK < nInh ? s + CHUNK : nInh;
            int blocks = (cend - s + EPB - 1) / EPB;
            scatter_kernel<<<blocks, THR, 0, stream>>>(
                inh_src, inh_dst, inh_k, inh_hill, x,
                cbuf, dloc, cur + (size_t)pass * nb, inh, s, cend, nb, cap);
            accum_kernel<<<nb, THR, 0, stream>>>(
                cbuf, dloc, cur + (size_t)pass * nb, cap, inh, n);
        }

        int finBlocks = ((n + 3) / 4 + 255) / 256;
        finalize_kernel<<<finBlocks, 256, 0, stream>>>(
            x, num, inh, log_decay, log_growth, log_nu, out, n);
    } else {
        // round-6 verified fallback: agent atomics
        float* fnum = (float*)ws;
        float* finh = (float*)(ws + (size_t)n * 4);
        hipMemsetAsync(d_ws, 0, (size_t)n * 8, stream);
        const int BLK = 256;
        int actBlocks = ((nAct + 3) / 4 + BLK - 1) / BLK;
        int inhBlocks = ((nInh + 3) / 4 + BLK - 1) / BLK;
        edge_kernel_fb<<<actBlocks, BLK, 0, stream>>>(act_src, act_dst, act_k, act_hill, x, fnum, nAct);
        edge_kernel_fb<<<inhBlocks, BLK, 0, stream>>>(inh_src, inh_dst, inh_k, inh_hill, x, finh, nInh);
        int finBlocks = ((n + 3) / 4 + BLK - 1) / BLK;
        finalize_kernel<<<finBlocks, BLK, 0, stream>>>(x, fnum, finh, log_decay, log_growth, log_nu, out, n);
    }
}